// Round 15
// baseline (402.055 us; speedup 1.0000x reference)
//
#include <hip/hip_runtime.h>
#include <hip/hip_cooperative_groups.h>
#include <hip/hip_bf16.h>
#include <math.h>

namespace cg = cooperative_groups;

#define LOG2PI_F 1.8378770664093453f

typedef int i32x4 __attribute__((ext_vector_type(4)));
typedef int i32x8 __attribute__((ext_vector_type(8)));
typedef float f32x4 __attribute__((ext_vector_type(4)));

#define M_DIM 16384
#define K_DIM 2048
#define N_DIM 2048
#define BM 256
#define BN 256
#define BK 128
#define NB_N (N_DIM / BN) /* 8 */
#define NB_M (M_DIM / BM) /* 64 */
#define LSCALE 256.0f
#define QDESCALE (1.0f / 65536.0f)
#define SCALE_ONE 0x7F7F7F7F   /* e8m0 biased 127 = 2^0 in all byte lanes */

__device__ __forceinline__ void gload16(const void* g, void* l) {
    __builtin_amdgcn_global_load_lds(
        (__attribute__((address_space(1))) void*)g,
        (__attribute__((address_space(3))) void*)l, 16, 0, 0);
}

__device__ __forceinline__ unsigned int pk4_fp8(float a, float b, float c, float d) {
    unsigned int w = (unsigned int)__builtin_amdgcn_cvt_pk_fp8_f32(a, b, 0, false);
    w = (unsigned int)__builtin_amdgcn_cvt_pk_fp8_f32(c, d, (int)w, true);
    return w;
}

__device__ __forceinline__ i32x8 frag128(const unsigned char* base, int roff, int g) {
    const unsigned char* rb = base + roff * 128;
    int x = (roff & 7) << 4;
    i32x4 lo = *(const i32x4*)(rb + (((g * 2) << 4) ^ x));
    i32x4 hi = *(const i32x4*)(rb + (((g * 2 + 1) << 4) ^ x));
    return __builtin_shufflevector(lo, hi, 0, 1, 2, 3, 4, 5, 6, 7);
}

#define MXMFMA(A, B, C) __builtin_amdgcn_mfma_scale_f32_16x16x128_f8f6f4( \
        (A), (B), (C), 0, 0, 0, SCALE_ONE, 0, SCALE_ONE)
#define BAR() asm volatile("s_barrier" ::: "memory")
#define WAITL() { asm volatile("s_waitcnt lgkmcnt(0)" ::: "memory"); \
                  __builtin_amdgcn_sched_barrier(0); }

union ShU {
    struct QQ { unsigned char As[2][BM * BK]; unsigned char Bs[2][BN * BK]; } q;
    struct PP { float tile[64][65]; float red[16]; } p;
    struct EE { double dred[6][8]; } e;
};

// ===========================================================================
// Cooperative mega-kernel: L-prep | grid.sync | X-prep | mb-flag sync |
// quad (R12 structure) | grid.sync | row-reduce | grid.sync | finalize.
// 256 blocks x 512 threads, 1 block/CU (128 KB LDS).
// ===========================================================================
__global__ __launch_bounds__(512, 2) void mega(const float* __restrict__ X,
                                               const float* __restrict__ Wm,
                                               const float* __restrict__ Woff,
                                               const float* __restrict__ Wld,
                                               const float* __restrict__ Y,
                                               const float* __restrict__ Cnt,
                                               const float* __restrict__ nld_p,
                                               unsigned char* __restrict__ Xq,
                                               unsigned char* __restrict__ Lq,
                                               float* __restrict__ U,
                                               float* __restrict__ qpart,
                                               float* __restrict__ misc,
                                               double* __restrict__ dpart,
                                               int* __restrict__ mbflag,
                                               float* __restrict__ out) {
    __shared__ ShU sh;
    cg::grid_group grid = cg::this_grid();
    const int bid = blockIdx.x;
    const int tid = threadIdx.x;
    const int lane = tid & 63;
    const int wid = tid >> 6;               // 0..7

    // ---------------- Phase A: L tiles (4 per block) ----------------
    for (int i = 0; i < 4; ++i) {
        const int t = bid * 4 + i;
        const int jt = (t & 31) * 64, it = (t >> 5) * 64;
        float ss = 0.f;
        if (it + 63 >= jt) {
            for (int e = tid; e < 4096; e += 512) {
                int r = e >> 6, c = e & 63;
                sh.p.tile[r][c] = Woff[(size_t)(it + r) * K_DIM + (jt + c)];
            }
        }
        __syncthreads();
        for (int e = tid; e < 4096; e += 512) {
            int jr = e >> 6, ic = e & 63;
            int ii = it + ic, jj = jt + jr;
            float v = 0.f;
            if (ii > jj) { v = sh.p.tile[ic][jr]; ss += v * v; }
            else if (ii == jj) v = expf(Wld[ii]);
            unsigned w = (unsigned)__builtin_amdgcn_cvt_pk_fp8_f32(v * LSCALE, 0.f, 0, false);
            Lq[(size_t)jj * K_DIM + ii] = (unsigned char)(w & 0xffu);
        }
        #pragma unroll
        for (int off = 32; off; off >>= 1) ss += __shfl_down(ss, off);
        if (lane == 0) sh.p.red[wid] = ss;
        __syncthreads();
        if (tid == 0) {
            float s = 0.f;
            #pragma unroll
            for (int w2 = 0; w2 < 8; ++w2) s += sh.p.red[w2];
            misc[t] = s;
        }
        __syncthreads();
    }
    __threadfence();
    grid.sync();    // Lq + misc visible everywhere

    // ---------------- Phase B: X rows (one row per wave, 8 batches) --------
    const int mymb = bid >> 2;
    for (int batch = 0; batch < 8; ++batch) {
        const int row = bid * 64 + batch * 8 + wid;
        const float* xr = X + (size_t)row * K_DIM;
        unsigned char* xo = Xq + (size_t)row * K_DIM;
        float dot = 0.f;
        #pragma unroll
        for (int c = 0; c < 8; ++c) {
            const int idx = c * 256 + lane * 4;
            float4 v = *(const float4*)(xr + idx);
            float4 w = *(const float4*)(Wm + idx);
            dot += v.x * w.x + v.y * w.y + v.z * w.z + v.w * w.w;
            *(unsigned*)(xo + idx) = pk4_fp8(v.x, v.y, v.z, v.w);
        }
        #pragma unroll
        for (int off = 32; off; off >>= 1) dot += __shfl_down(dot, off);
        if (lane == 0) U[row] = dot;
    }
    __threadfence();
    __syncthreads();
    if (tid == 0) {
        __hip_atomic_fetch_add(&mbflag[mymb], 1, __ATOMIC_RELEASE, __HIP_MEMORY_SCOPE_AGENT);
        while (__hip_atomic_load(&mbflag[mymb], __ATOMIC_ACQUIRE, __HIP_MEMORY_SCOPE_AGENT) < 4)
            __builtin_amdgcn_s_sleep(2);
    }
    __syncthreads();
    __threadfence();

    // ---------------- Phase C: quad GEMM (R12 structure, verbatim) ---------
    {
        const int mb = bid >> 2;
        const int jp = bid & 3;
        const int wr = wid >> 2, wc = wid & 3;  // 2M x 4N wave grid
        const int g = lane >> 4, r16 = lane & 15;
        const int brow = mb * BM;
        const int srow = lane >> 3;
        const int scol = (lane & 7) ^ srow;

        auto gemm_one = [&](int nb) {
            const int bcol = nb * BN;
            const int NT = (K_DIM - bcol) >> 7;   // 16 - 2*nb, in [2,16]

            const unsigned char* pA[2];
            const unsigned char* pB[2];
            #pragma unroll
            for (int h = 0; h < 2; ++h) {
                pA[h] = Xq + (size_t)(brow + h * 128 + wid * 16 + srow) * K_DIM + bcol + scol * 16;
                pB[h] = Lq + (size_t)(bcol + h * 128 + wid * 16 + srow) * K_DIM + bcol + scol * 16;
            }

            auto stgA = [&](int t, int h, int buf) {
                const unsigned char* s = pA[h] + (size_t)t * 128;
                char* d = (char*)sh.q.As[buf] + h * 16384 + wid * 2048;
                gload16(s, d);
                gload16(s + (size_t)8 * K_DIM, d + 1024);
            };
            auto stgB = [&](int t, int h, int buf) {
                const unsigned char* s = pB[h] + (size_t)t * 128;
                char* d = (char*)sh.q.Bs[buf] + h * 16384 + wid * 2048;
                gload16(s, d);
                gload16(s + (size_t)8 * K_DIM, d + 1024);
            };

            f32x4 acc[8][4];
            const f32x4 zero = {0.f, 0.f, 0.f, 0.f};
            #pragma unroll
            for (int m = 0; m < 8; ++m)
                #pragma unroll
                for (int n = 0; n < 4; ++n) acc[m][n] = zero;

            stgA(0, 0, 0); stgA(0, 1, 0); stgB(0, 0, 0); stgB(0, 1, 0);
            stgB(1, 0, 1); stgB(1, 1, 1);
            asm volatile("s_waitcnt vmcnt(4)" ::: "memory");
            BAR();

            for (int t = 0; t < NT; ++t) {
                const int cur = t & 1, nbuf = cur ^ 1;
                const unsigned char* Abase = sh.q.As[cur] + wr * 16384;
                const unsigned char* Bbase = sh.q.Bs[cur] + (wc >> 1) * 16384;
                const int brow2 = (wc & 1) * 64;
                const bool s1 = (t + 1 < NT), s2 = (t + 2 < NT);
                i32x8 bf[4], af[4];

                #pragma unroll
                for (int n = 0; n < 4; ++n) bf[n] = frag128(Bbase, brow2 + n * 16 + r16, g);
                #pragma unroll
                for (int m = 0; m < 4; ++m) af[m] = frag128(Abase, m * 16 + r16, g);
                if (s1) { stgA(t + 1, 0, nbuf); stgA(t + 1, 1, nbuf); }
                BAR();
                WAITL();
                __builtin_amdgcn_s_setprio(1);
                #pragma unroll
                for (int m = 0; m < 4; ++m)
                    #pragma unroll
                    for (int n = 0; n < 4; ++n)
                        acc[m][n] = MXMFMA(af[m], bf[n], acc[m][n]);
                __builtin_amdgcn_s_setprio(0);
                BAR();

                #pragma unroll
                for (int m = 0; m < 4; ++m) af[m] = frag128(Abase, 64 + m * 16 + r16, g);
                if (s2) { stgB(t + 2, 0, cur); stgB(t + 2, 1, cur); }
                BAR();
                WAITL();
                __builtin_amdgcn_s_setprio(1);
                #pragma unroll
                for (int m = 0; m < 4; ++m)
                    #pragma unroll
                    for (int n = 0; n < 4; ++n)
                        acc[4 + m][n] = MXMFMA(af[m], bf[n], acc[4 + m][n]);
                __builtin_amdgcn_s_setprio(0);

                if (s2)
                    asm volatile("s_waitcnt vmcnt(4)" ::: "memory");
                else if (s1)
                    asm volatile("s_waitcnt vmcnt(0)" ::: "memory");
                BAR();
            }

            float* qbuf = (float*)&sh.q.As[0][0];
            __syncthreads();
            #pragma unroll
            for (int m = 0; m < 8; ++m) {
                #pragma unroll
                for (int r = 0; r < 4; ++r) {
                    float s = 0.f;
                    #pragma unroll
                    for (int n = 0; n < 4; ++n) {
                        float t2 = acc[m][n][r];
                        s += t2 * t2;
                    }
                    #pragma unroll
                    for (int off = 1; off < 16; off <<= 1) s += __shfl_xor(s, off);
                    if (r16 == 0) qbuf[wc * 256 + wr * 128 + m * 16 + g * 4 + r] = s;
                }
            }
            __syncthreads();
            if (tid < BM)
                qpart[(size_t)(brow + tid) * NB_N + nb] =
                    (qbuf[tid] + qbuf[256 + tid] + qbuf[512 + tid] + qbuf[768 + tid]) * QDESCALE;
            __syncthreads();
        };

        gemm_one(jp);        // heavy: NT = 16 - 2*jp
        gemm_one(7 - jp);    // light: NT = 2 + 2*jp; sum = 18 always
    }
    __threadfence();
    grid.sync();    // qpart visible

    // ---------------- Phase D: row reduction (wave 0, 64 rows/block) -------
    {
        const float nld = nld_p[0];
        const float inv_sig = expf(-nld);
        const float nprec = inv_sig * inv_sig;
        if (wid == 0) {
            const int row = bid * 64 + lane;
            const float4* qp = (const float4*)(qpart + (size_t)row * NB_N);
            float4 q0 = qp[0], q1 = qp[1];
            float q = q0.x + q0.y + q0.z + q0.w + q1.x + q1.y + q1.z + q1.w;
            float c = Cnt[row];
            float d = (Y[row] - U[row]) * inv_sig;
            float pl = -0.5f * d * d - nld - 0.5f * LOG2PI_F;
            float tt = 0.5f * q * c * c * nprec;
            double s1 = (double)c;
            double s2 = (double)((pl - tt) * c);
            #pragma unroll
            for (int off = 32; off; off >>= 1) {
                s1 += __shfl_down(s1, off);
                s2 += __shfl_down(s2, off);
            }
            if (lane == 0) {
                dpart[bid * 2 + 0] = s1;
                dpart[bid * 2 + 1] = s2;
            }
        }
    }
    __threadfence();
    grid.sync();    // dpart visible

    // ---------------- Phase E: final combine (block 0 only) ----------------
    if (bid == 0) {
        const float nld = nld_p[0];
        const float inv_sig = expf(-nld);
        const float nprec = inv_sig * inv_sig;

        double s1 = 0.0, s2 = 0.0;
        if (tid < 256) { s1 = dpart[tid * 2]; s2 = dpart[tid * 2 + 1]; }

        double wm2 = 0.0, tcd = 0.0, wls = 0.0, offs = 0.0;
        for (int i = tid; i < K_DIM; i += 512) {
            float w = Wm[i];
            wm2 += (double)w * (double)w;
            float ld = Wld[i];
            tcd += exp(2.0 * (double)ld);
            wls += (double)ld;
        }
        for (int i = tid; i < 1024; i += 512) offs += (double)misc[i];

        double vals[6] = {s1, s2, wm2, tcd, wls, offs};
        __syncthreads();   // LDS phase transition
        #pragma unroll
        for (int s = 0; s < 6; ++s) {
            double v = vals[s];
            #pragma unroll
            for (int off = 32; off; off >>= 1) v += __shfl_down(v, off);
            if (lane == 0) sh.e.dred[s][wid] = v;
        }
        __syncthreads();
        if (tid == 0) {
            double acc6[6];
            #pragma unroll
            for (int s = 0; s < 6; ++s) {
                double v = 0.0;
                #pragma unroll
                for (int w2 = 0; w2 < 8; ++w2) v += sh.e.dred[s][w2];
                acc6[s] = v;
            }
            double trace_cov = acc6[5] + acc6[3];
            double kl = 0.5 * (acc6[2] + trace_cov - 2.0 * acc6[4]);
            double wish = 1.5 * (-2.0 * (double)nld) - 0.005 * (double)nprec;
            double elbo = acc6[1] / acc6[0] + 1e-4 * (wish - kl);
            out[0] = (float)(-elbo);
        }
    }
}

// ===========================================================================
// Fallback path (R14 kernels) -- used only if cooperative launch fails.
// ===========================================================================
__global__ __launch_bounds__(256) void prep_fused(const float* __restrict__ X,
                                                  const float* __restrict__ Wm,
                                                  const float* __restrict__ Woff,
                                                  const float* __restrict__ Wld,
                                                  unsigned char* __restrict__ Xq,
                                                  unsigned char* __restrict__ Lq,
                                                  float* __restrict__ U,
                                                  float* __restrict__ misc_arr) {
    __shared__ float tile[64][65];
    __shared__ float red[4];
    const int bid = blockIdx.x;
    const int tid = threadIdx.x;

    if (bid < 1024) {
        const int jt = (bid & 31) * 64;
        const int it = (bid >> 5) * 64;
        float ss = 0.f;
        if (it + 63 >= jt) {
            for (int e = tid; e < 4096; e += 256) {
                int r = e >> 6, c = e & 63;
                tile[r][c] = Woff[(size_t)(it + r) * K_DIM + (jt + c)];
            }
        }
        __syncthreads();
        for (int e = tid; e < 4096; e += 256) {
            int jr = e >> 6, ic = e & 63;
            int i = it + ic, j = jt + jr;
            float v = 0.f;
            if (i > j) { v = tile[ic][jr]; ss += v * v; }
            else if (i == j) v = expf(Wld[i]);
            unsigned int w = (unsigned int)__builtin_amdgcn_cvt_pk_fp8_f32(v * LSCALE, 0.f, 0, false);
            Lq[(size_t)j * K_DIM + i] = (unsigned char)(w & 0xffu);
        }
        #pragma unroll
        for (int off = 32; off; off >>= 1) ss += __shfl_down(ss, off);
        if ((tid & 63) == 0) red[tid >> 6] = ss;
        __syncthreads();
        if (tid == 0) misc_arr[bid] = red[0] + red[1] + red[2] + red[3];
    } else {
        const int b = bid - 1024;
        const float* xr = X + (size_t)b * K_DIM;
        unsigned char* xo = Xq + (size_t)b * K_DIM;
        const int base = tid * 8;
        float4 v0 = *(const float4*)(xr + base);
        float4 v1 = *(const float4*)(xr + base + 4);
        float4 w0 = *(const float4*)(Wm + base);
        float4 w1 = *(const float4*)(Wm + base + 4);
        float dot = v0.x * w0.x + v0.y * w0.y + v0.z * w0.z + v0.w * w0.w
                  + v1.x * w1.x + v1.y * w1.y + v1.z * w1.z + v1.w * w1.w;
        uint2 p;
        p.x = pk4_fp8(v0.x, v0.y, v0.z, v0.w);
        p.y = pk4_fp8(v1.x, v1.y, v1.z, v1.w);
        *(uint2*)(xo + base) = p;
        #pragma unroll
        for (int off = 32; off; off >>= 1) dot += __shfl_down(dot, off);
        if ((tid & 63) == 0) red[tid >> 6] = dot;
        __syncthreads();
        if (tid == 0) U[b] = red[0] + red[1] + red[2] + red[3];
    }
}

__global__ __launch_bounds__(512, 2) void quad_gemm(const unsigned char* __restrict__ Xq,
                                                    const unsigned char* __restrict__ Lq,
                                                    float* __restrict__ qpart) {
    __shared__ unsigned char As[2][BM * BK];
    __shared__ unsigned char Bs[2][BN * BK];

    const int mb = blockIdx.x;
    const int jp = blockIdx.y;
    const int tid = threadIdx.x;
    const int lane = tid & 63;
    const int wid = tid >> 6;
    const int wr = wid >> 2, wc = wid & 3;
    const int g = lane >> 4, r16 = lane & 15;
    const int brow = mb * BM;
    const int srow = lane >> 3;
    const int scol = (lane & 7) ^ srow;

    auto gemm_one = [&](int nb) {
        const int bcol = nb * BN;
        const int NT = (K_DIM - bcol) >> 7;

        const unsigned char* pA[2];
        const unsigned char* pB[2];
        #pragma unroll
        for (int h = 0; h < 2; ++h) {
            pA[h] = Xq + (size_t)(brow + h * 128 + wid * 16 + srow) * K_DIM + bcol + scol * 16;
            pB[h] = Lq + (size_t)(bcol + h * 128 + wid * 16 + srow) * K_DIM + bcol + scol * 16;
        }
        auto stgA = [&](int t, int h, int buf) {
            const unsigned char* s = pA[h] + (size_t)t * 128;
            char* d = (char*)As[buf] + h * 16384 + wid * 2048;
            gload16(s, d);
            gload16(s + (size_t)8 * K_DIM, d + 1024);
        };
        auto stgB = [&](int t, int h, int buf) {
            const unsigned char* s = pB[h] + (size_t)t * 128;
            char* d = (char*)Bs[buf] + h * 16384 + wid * 2048;
            gload16(s, d);
            gload16(s + (size_t)8 * K_DIM, d + 1024);
        };

        f32x4 acc[8][4];
        const f32x4 zero = {0.f, 0.f, 0.f, 0.f};
        #pragma unroll
        for (int m = 0; m < 8; ++m)
            #pragma unroll
            for (int n = 0; n < 4; ++n) acc[m][n] = zero;

        stgA(0, 0, 0); stgA(0, 1, 0); stgB(0, 0, 0); stgB(0, 1, 0);
        stgB(1, 0, 1); stgB(1, 1, 1);
        asm volatile("s_waitcnt vmcnt(4)" ::: "memory");
        BAR();

        for (int t = 0; t < NT; ++t) {
            const int cur = t & 1, nbuf = cur ^ 1;
            const unsigned char* Abase = As[cur] + wr * 16384;
            const unsigned char* Bbase = Bs[cur] + (wc >> 1) * 16384;
            const int brow2 = (wc & 1) * 64;
            const bool s1 = (t + 1 < NT), s2 = (t + 2 < NT);
            i32x8 bf[4], af[4];

            #pragma unroll
            for (int n = 0; n < 4; ++n) bf[n] = frag128(Bbase, brow2 + n * 16 + r16, g);
            #pragma unroll
            for (int m = 0; m < 4; ++m) af[m] = frag128(Abase, m * 16 + r16, g);
            if (s1) { stgA(t + 1, 0, nbuf); stgA(t + 1, 1, nbuf); }
            BAR();
            WAITL();
            __builtin_amdgcn_s_setprio(1);
            #pragma unroll
            for (int m = 0; m < 4; ++m)
                #pragma unroll
                for (int n = 0; n < 4; ++n)
                    acc[m][n] = MXMFMA(af[m], bf[n], acc[m][n]);
            __builtin_amdgcn_s_setprio(0);
            BAR();

            #pragma unroll
            for (int m = 0; m < 4; ++m) af[m] = frag128(Abase, 64 + m * 16 + r16, g);
            if (s2) { stgB(t + 2, 0, cur); stgB(t + 2, 1, cur); }
            BAR();
            WAITL();
            __builtin_amdgcn_s_setprio(1);
            #pragma unroll
            for (int m = 0; m < 4; ++m)
                #pragma unroll
                for (int n = 0; n < 4; ++n)
                    acc[4 + m][n] = MXMFMA(af[m], bf[n], acc[4 + m][n]);
            __builtin_amdgcn_s_setprio(0);

            if (s2)      asm volatile("s_waitcnt vmcnt(4)" ::: "memory");
            else if (s1) asm volatile("s_waitcnt vmcnt(0)" ::: "memory");
            BAR();
        }

        float* qbuf = (float*)&As[0][0];
        __syncthreads();
        #pragma unroll
        for (int m = 0; m < 8; ++m) {
            #pragma unroll
            for (int r = 0; r < 4; ++r) {
                float s = 0.f;
                #pragma unroll
                for (int n = 0; n < 4; ++n) {
                    float t2 = acc[m][n][r];
                    s += t2 * t2;
                }
                #pragma unroll
                for (int off = 1; off < 16; off <<= 1) s += __shfl_xor(s, off);
                if (r16 == 0) qbuf[wc * 256 + wr * 128 + m * 16 + g * 4 + r] = s;
            }
        }
        __syncthreads();
        if (tid < BM)
            qpart[(size_t)(brow + tid) * NB_N + nb] =
                (qbuf[tid] + qbuf[256 + tid] + qbuf[512 + tid] + qbuf[768 + tid]) * QDESCALE;
        __syncthreads();
    };

    gemm_one(jp);
    gemm_one(7 - jp);
}

__global__ __launch_bounds__(256) void row_part(const float* __restrict__ Y,
                                                const float* __restrict__ Cnt,
                                                const float* __restrict__ nld_p,
                                                const float* __restrict__ U,
                                                const float* __restrict__ qpart,
                                                double* __restrict__ dpart) {
    const int tid = threadIdx.x;
    const float nld = nld_p[0];
    const float inv_sig = expf(-nld);
    const float nprec = inv_sig * inv_sig;
    double s1 = 0.0, s2 = 0.0;
    const int base = blockIdx.x * 512;
    #pragma unroll
    for (int j = 0; j < 2; ++j) {
        int b = base + j * 256 + tid;
        float c = Cnt[b];
        const float4* qp = (const float4*)(qpart + (size_t)b * NB_N);
        float4 q0 = qp[0], q1 = qp[1];
        float q = q0.x + q0.y + q0.z + q0.w + q1.x + q1.y + q1.z + q1.w;
        float d = (Y[b] - U[b]) * inv_sig;
        float pl = -0.5f * d * d - nld - 0.5f * LOG2PI_F;
        float tt = 0.5f * q * c * c * nprec;
        s1 += (double)c;
        s2 += (double)((pl - tt) * c);
    }
    __shared__ double red[2][4];
    #pragma unroll
    for (int off = 32; off; off >>= 1) {
        s1 += __shfl_down(s1, off);
        s2 += __shfl_down(s2, off);
    }
    if ((tid & 63) == 0) { red[0][tid >> 6] = s1; red[1][tid >> 6] = s2; }
    __syncthreads();
    if (tid == 0) {
        dpart[blockIdx.x * 2 + 0] = red[0][0] + red[0][1] + red[0][2] + red[0][3];
        dpart[blockIdx.x * 2 + 1] = red[1][0] + red[1][1] + red[1][2] + red[1][3];
    }
}

__global__ __launch_bounds__(256) void finalize2(const float* __restrict__ nld_p,
                                                 const float* __restrict__ Wm,
                                                 const float* __restrict__ Wld,
                                                 const double* __restrict__ dpart,
                                                 const float* __restrict__ misc_arr,
                                                 float* __restrict__ out) {
    const int tid = threadIdx.x;
    const float nld = nld_p[0];
    const float inv_sig = expf(-nld);
    const float nprec = inv_sig * inv_sig;

    double s1 = 0.0, s2 = 0.0;
    if (tid < 32) { s1 = dpart[tid * 2]; s2 = dpart[tid * 2 + 1]; }

    double wm2 = 0.0, tcd = 0.0, wls = 0.0, offs = 0.0;
    for (int i = tid; i < K_DIM; i += 256) {
        float w = Wm[i];
        wm2 += (double)w * (double)w;
        float ld = Wld[i];
        tcd += exp(2.0 * (double)ld);
        wls += (double)ld;
    }
    for (int i = tid; i < 1024; i += 256) offs += (double)misc_arr[i];

    __shared__ double red[6][4];
    double vals[6] = {s1, s2, wm2, tcd, wls, offs};
    #pragma unroll
    for (int s = 0; s < 6; ++s) {
        double v = vals[s];
        #pragma unroll
        for (int off = 32; off; off >>= 1) v += __shfl_down(v, off);
        if ((tid & 63) == 0) red[s][tid >> 6] = v;
    }
    __syncthreads();
    if (tid == 0) {
        double S1 = red[0][0] + red[0][1] + red[0][2] + red[0][3];
        double S2 = red[1][0] + red[1][1] + red[1][2] + red[1][3];
        double MSE = red[2][0] + red[2][1] + red[2][2] + red[2][3];
        double TCD = red[3][0] + red[3][1] + red[3][2] + red[3][3];
        double WLS = red[4][0] + red[4][1] + red[4][2] + red[4][3];
        double OFFS = red[5][0] + red[5][1] + red[5][2] + red[5][3];
        double trace_cov = OFFS + TCD;
        double kl = 0.5 * (MSE + trace_cov - 2.0 * WLS);
        double wish = 1.5 * (-2.0 * (double)nld) - 0.005 * (double)nprec;
        double elbo = S2 / S1 + 1e-4 * (wish - kl);
        out[0] = (float)(-elbo);
    }
}

// ---------------------------------------------------------------------------
extern "C" void kernel_launch(void* const* d_in, const int* in_sizes, int n_in,
                              void* d_out, int out_size, void* d_ws, size_t ws_size,
                              hipStream_t stream) {
    const float* x    = (const float*)d_in[0];
    const float* y    = (const float*)d_in[1];
    const float* cnt  = (const float*)d_in[2];
    // d_in[3] = noise_mean (unused by the reference math)
    const float* nld  = (const float*)d_in[4];
    const float* Wm   = (const float*)d_in[5];
    const float* Wld  = (const float*)d_in[6];
    const float* Woff = (const float*)d_in[7];

    char* ws = (char*)d_ws;
    unsigned char* Xq = (unsigned char*)(ws);              // 33554432 B
    unsigned char* Lq = (unsigned char*)(ws + 33554432);   // 4194304 B
    double* dpart  = (double*)(ws + 40000000);             // 4096 B
    int*    mbflag = (int*)(ws + 40008192);                // 256 B
    float*  U      = (float*)(ws + 75497472);              // 64 KB
    float*  qpart  = (float*)(ws + 75563008);              // 512 KB
    float*  misc   = (float*)(ws + 76611584);              // 4 KB
    float*  outp   = (float*)d_out;

    hipMemsetAsync(mbflag, 0, 64 * sizeof(int), stream);

    void* kargs[] = {
        (void*)&x, (void*)&Wm, (void*)&Woff, (void*)&Wld, (void*)&y,
        (void*)&cnt, (void*)&nld, (void*)&Xq, (void*)&Lq, (void*)&U,
        (void*)&qpart, (void*)&misc, (void*)&dpart, (void*)&mbflag, (void*)&outp
    };
    hipError_t err = hipLaunchCooperativeKernel(
        reinterpret_cast<void*>(mega), dim3(256), dim3(512), kargs, 0, stream);

    if (err != hipSuccess) {
        // Fallback: proven R14 4-kernel path.
        prep_fused<<<dim3(1024 + M_DIM), 256, 0, stream>>>(x, Wm, Woff, Wld, Xq, Lq, U, misc);
        quad_gemm<<<dim3(NB_M, 4), 512, 0, stream>>>(Xq, Lq, qpart);
        row_part<<<dim3(32), 256, 0, stream>>>(y, cnt, nld, U, qpart, dpart);
        finalize2<<<1, 256, 0, stream>>>(nld, Wm, Wld, dpart, misc, outp);
    }
}

// Round 16
// 132.138 us; speedup vs baseline: 3.0427x; 3.0427x over previous
//
#include <hip/hip_runtime.h>
#include <hip/hip_bf16.h>
#include <math.h>

#define LOG2PI_F 1.8378770664093453f

typedef int i32x4 __attribute__((ext_vector_type(4)));
typedef int i32x8 __attribute__((ext_vector_type(8)));
typedef float f32x4 __attribute__((ext_vector_type(4)));

#define M_DIM 16384
#define K_DIM 2048
#define N_DIM 2048
#define BM 256
#define BN 256
#define BK 128
#define NB_N (N_DIM / BN) /* 8 */
#define NB_M (M_DIM / BM) /* 64 */
#define LSCALE 256.0f
#define QDESCALE (1.0f / 65536.0f)
#define SCALE_ONE 0x7F7F7F7F   /* e8m0 biased 127 = 2^0 in all byte lanes */

// async global->LDS, 16B per lane. LDS dest is wave-uniform base + lane*16.
__device__ __forceinline__ void gload16(const void* g, void* l) {
    __builtin_amdgcn_global_load_lds(
        (__attribute__((address_space(1))) void*)g,
        (__attribute__((address_space(3))) void*)l, 16, 0, 0);
}

// pack 4 floats -> 4 e4m3 bytes (HW RNE+sat, OCP on gfx950)
__device__ __forceinline__ unsigned int pk4_fp8(float a, float b, float c, float d) {
    unsigned int w = (unsigned int)__builtin_amdgcn_cvt_pk_fp8_f32(a, b, 0, false);
    w = (unsigned int)__builtin_amdgcn_cvt_pk_fp8_f32(c, d, (int)w, true);
    return w;
}

// ---------------------------------------------------------------------------
// prep_fused (unchanged from R14, measured good): blocks [0,1024) build Lq
// (fp8 L^T, x256) + Woff^2 partials; blocks [1024,1024+16384) cast X->fp8
// and compute the pred_mean GEMV. Independent jobs run concurrently.
// ---------------------------------------------------------------------------
__global__ __launch_bounds__(256) void prep_fused(const float* __restrict__ X,
                                                  const float* __restrict__ Wm,
                                                  const float* __restrict__ Woff,
                                                  const float* __restrict__ Wld,
                                                  unsigned char* __restrict__ Xq,
                                                  unsigned char* __restrict__ Lq,
                                                  float* __restrict__ U,
                                                  float* __restrict__ misc_arr) {
    __shared__ float tile[64][65];
    __shared__ float red[4];
    const int bid = blockIdx.x;
    const int tid = threadIdx.x;

    if (bid < 1024) {
        const int jt = (bid & 31) * 64;
        const int it = (bid >> 5) * 64;
        float ss = 0.f;
        if (it + 63 >= jt) {
            for (int e = tid; e < 4096; e += 256) {
                int r = e >> 6, c = e & 63;
                tile[r][c] = Woff[(size_t)(it + r) * K_DIM + (jt + c)];
            }
        }
        __syncthreads();
        for (int e = tid; e < 4096; e += 256) {
            int jr = e >> 6, ic = e & 63;
            int i = it + ic, j = jt + jr;
            float v = 0.f;
            if (i > j) { v = tile[ic][jr]; ss += v * v; }
            else if (i == j) v = expf(Wld[i]);
            unsigned int w = (unsigned int)__builtin_amdgcn_cvt_pk_fp8_f32(v * LSCALE, 0.f, 0, false);
            Lq[(size_t)j * K_DIM + i] = (unsigned char)(w & 0xffu);
        }
        #pragma unroll
        for (int off = 32; off; off >>= 1) ss += __shfl_down(ss, off);
        if ((tid & 63) == 0) red[tid >> 6] = ss;
        __syncthreads();
        if (tid == 0) misc_arr[bid] = red[0] + red[1] + red[2] + red[3];
    } else {
        const int b = bid - 1024;
        const float* xr = X + (size_t)b * K_DIM;
        unsigned char* xo = Xq + (size_t)b * K_DIM;
        const int base = tid * 8;
        float4 v0 = *(const float4*)(xr + base);
        float4 v1 = *(const float4*)(xr + base + 4);
        float4 w0 = *(const float4*)(Wm + base);
        float4 w1 = *(const float4*)(Wm + base + 4);
        float dot = v0.x * w0.x + v0.y * w0.y + v0.z * w0.z + v0.w * w0.w
                  + v1.x * w1.x + v1.y * w1.y + v1.z * w1.z + v1.w * w1.w;
        uint2 p;
        p.x = pk4_fp8(v0.x, v0.y, v0.z, v0.w);
        p.y = pk4_fp8(v1.x, v1.y, v1.z, v1.w);
        *(uint2*)(xo + base) = p;
        #pragma unroll
        for (int off = 32; off; off >>= 1) dot += __shfl_down(dot, off);
        if ((tid & 63) == 0) red[tid >> 6] = dot;
        __syncthreads();
        if (tid == 0) U[b] = red[0] + red[1] + red[2] + red[3];
    }
}

// ---------------------------------------------------------------------------
// quad_all: R12 quad structure (measured best) + no-spin reduction tail.
// After its two GEMMs, each block bumps mbcnt[mb] (ACQ_REL, agent scope):
// the 4th sibling of the mb-group reduces the panel's 256 rows into
// dpart[mb], bumps gcnt; the 64th such block runs the finalize and writes
// out. Non-last blocks exit immediately -- no waiting anywhere.
// ---------------------------------------------------------------------------
__device__ __forceinline__ i32x8 frag128(const unsigned char* base, int roff, int g) {
    const unsigned char* rb = base + roff * 128;
    int x = (roff & 7) << 4;
    i32x4 lo = *(const i32x4*)(rb + (((g * 2) << 4) ^ x));
    i32x4 hi = *(const i32x4*)(rb + (((g * 2 + 1) << 4) ^ x));
    return __builtin_shufflevector(lo, hi, 0, 1, 2, 3, 4, 5, 6, 7);
}

#define MXMFMA(A, B, C) __builtin_amdgcn_mfma_scale_f32_16x16x128_f8f6f4( \
        (A), (B), (C), 0, 0, 0, SCALE_ONE, 0, SCALE_ONE)
#define BAR() asm volatile("s_barrier" ::: "memory")
#define WAITL() { asm volatile("s_waitcnt lgkmcnt(0)" ::: "memory"); \
                  __builtin_amdgcn_sched_barrier(0); }

__global__ __launch_bounds__(512, 2) void quad_all(const unsigned char* __restrict__ Xq,
                                                   const unsigned char* __restrict__ Lq,
                                                   float* __restrict__ qpart,
                                                   const float* __restrict__ Y,
                                                   const float* __restrict__ Cnt,
                                                   const float* __restrict__ nld_p,
                                                   const float* __restrict__ U,
                                                   const float* __restrict__ Wm,
                                                   const float* __restrict__ Wld,
                                                   const float* __restrict__ misc,
                                                   double* __restrict__ dpart,
                                                   int* __restrict__ mbcnt,
                                                   int* __restrict__ gcnt,
                                                   float* __restrict__ out) {
    __shared__ unsigned char As[2][BM * BK];   // 2 x 32 KB
    __shared__ unsigned char Bs[2][BN * BK];   // 2 x 32 KB (128 KB total)
    __shared__ int s_f1, s_f2;

    const int mb = blockIdx.x;
    const int jp = blockIdx.y;              // 0..3
    const int tid = threadIdx.x;
    const int lane = tid & 63;
    const int wid = tid >> 6;               // 0..7
    const int wr = wid >> 2, wc = wid & 3;  // 2M x 4N wave grid
    const int g = lane >> 4, r16 = lane & 15;
    const int brow = mb * BM;
    const int srow = lane >> 3;             // 0..7 == (lds row & 7)
    const int scol = (lane & 7) ^ srow;     // pre-swizzled 16B source chunk

    auto gemm_one = [&](int nb) {
        const int bcol = nb * BN;
        const int NT = (K_DIM - bcol) >> 7;   // 16 - 2*nb, in [2,16]

        const unsigned char* pA[2];
        const unsigned char* pB[2];
        #pragma unroll
        for (int h = 0; h < 2; ++h) {
            pA[h] = Xq + (size_t)(brow + h * 128 + wid * 16 + srow) * K_DIM + bcol + scol * 16;
            pB[h] = Lq + (size_t)(bcol + h * 128 + wid * 16 + srow) * K_DIM + bcol + scol * 16;
        }
        auto stgA = [&](int t, int h, int buf) {
            const unsigned char* s = pA[h] + (size_t)t * 128;
            char* d = (char*)As[buf] + h * 16384 + wid * 2048;
            gload16(s, d);
            gload16(s + (size_t)8 * K_DIM, d + 1024);
        };
        auto stgB = [&](int t, int h, int buf) {
            const unsigned char* s = pB[h] + (size_t)t * 128;
            char* d = (char*)Bs[buf] + h * 16384 + wid * 2048;
            gload16(s, d);
            gload16(s + (size_t)8 * K_DIM, d + 1024);
        };

        f32x4 acc[8][4];
        const f32x4 zero = {0.f, 0.f, 0.f, 0.f};
        #pragma unroll
        for (int m = 0; m < 8; ++m)
            #pragma unroll
            for (int n = 0; n < 4; ++n) acc[m][n] = zero;

        stgA(0, 0, 0); stgA(0, 1, 0); stgB(0, 0, 0); stgB(0, 1, 0);
        stgB(1, 0, 1); stgB(1, 1, 1);
        asm volatile("s_waitcnt vmcnt(4)" ::: "memory");
        BAR();

        for (int t = 0; t < NT; ++t) {
            const int cur = t & 1, nbuf = cur ^ 1;
            const unsigned char* Abase = As[cur] + wr * 16384;
            const unsigned char* Bbase = Bs[cur] + (wc >> 1) * 16384;
            const int brow2 = (wc & 1) * 64;
            const bool s1 = (t + 1 < NT), s2 = (t + 2 < NT);
            i32x8 bf[4], af[4];

            #pragma unroll
            for (int n = 0; n < 4; ++n) bf[n] = frag128(Bbase, brow2 + n * 16 + r16, g);
            #pragma unroll
            for (int m = 0; m < 4; ++m) af[m] = frag128(Abase, m * 16 + r16, g);
            if (s1) { stgA(t + 1, 0, nbuf); stgA(t + 1, 1, nbuf); }
            BAR();
            WAITL();
            __builtin_amdgcn_s_setprio(1);
            #pragma unroll
            for (int m = 0; m < 4; ++m)
                #pragma unroll
                for (int n = 0; n < 4; ++n)
                    acc[m][n] = MXMFMA(af[m], bf[n], acc[m][n]);
            __builtin_amdgcn_s_setprio(0);
            BAR();

            #pragma unroll
            for (int m = 0; m < 4; ++m) af[m] = frag128(Abase, 64 + m * 16 + r16, g);
            if (s2) { stgB(t + 2, 0, cur); stgB(t + 2, 1, cur); }
            BAR();
            WAITL();
            __builtin_amdgcn_s_setprio(1);
            #pragma unroll
            for (int m = 0; m < 4; ++m)
                #pragma unroll
                for (int n = 0; n < 4; ++n)
                    acc[4 + m][n] = MXMFMA(af[m], bf[n], acc[4 + m][n]);
            __builtin_amdgcn_s_setprio(0);

            if (s2)      asm volatile("s_waitcnt vmcnt(4)" ::: "memory");
            else if (s1) asm volatile("s_waitcnt vmcnt(0)" ::: "memory");
            BAR();
        }

        float* qbuf = (float*)&As[0][0];
        __syncthreads();
        #pragma unroll
        for (int m = 0; m < 8; ++m) {
            #pragma unroll
            for (int r = 0; r < 4; ++r) {
                float s = 0.f;
                #pragma unroll
                for (int n = 0; n < 4; ++n) {
                    float t2 = acc[m][n][r];
                    s += t2 * t2;
                }
                #pragma unroll
                for (int off = 1; off < 16; off <<= 1) s += __shfl_xor(s, off);
                if (r16 == 0) qbuf[wc * 256 + wr * 128 + m * 16 + g * 4 + r] = s;
            }
        }
        __syncthreads();
        if (tid < BM)
            qpart[(size_t)(brow + tid) * NB_N + nb] =
                (qbuf[tid] + qbuf[256 + tid] + qbuf[512 + tid] + qbuf[768 + tid]) * QDESCALE;
        __syncthreads();
    };

    gemm_one(jp);        // heavy: NT = 16 - 2*jp
    gemm_one(7 - jp);    // light: NT = 2 + 2*jp; sum = 18 always

    // ---------------- tail 1: mb-group last block reduces its 256 rows ----
    __threadfence();
    if (tid == 0)
        s_f1 = __hip_atomic_fetch_add(&mbcnt[mb], 1, __ATOMIC_ACQ_REL, __HIP_MEMORY_SCOPE_AGENT);
    __syncthreads();
    if (s_f1 != 3) return;   // not the last sibling -> done

    const float nld = nld_p[0];
    const float inv_sig = expf(-nld);
    const float nprec = inv_sig * inv_sig;

    double s1 = 0.0, s2 = 0.0;
    if (tid < 256) {
        const int row = brow + tid;
        const float4* qp = (const float4*)(qpart + (size_t)row * NB_N);
        float4 q0 = qp[0], q1 = qp[1];
        float q = q0.x + q0.y + q0.z + q0.w + q1.x + q1.y + q1.z + q1.w;
        float c = Cnt[row];
        float d = (Y[row] - U[row]) * inv_sig;
        float pl = -0.5f * d * d - nld - 0.5f * LOG2PI_F;
        float tt = 0.5f * q * c * c * nprec;
        s1 = (double)c;
        s2 = (double)((pl - tt) * c);
    }
    #pragma unroll
    for (int off = 32; off; off >>= 1) {
        s1 += __shfl_down(s1, off);
        s2 += __shfl_down(s2, off);
    }
    {
        double* dred = (double*)&As[0][0];   // LDS reuse (post-sync)
        if (lane == 0) { dred[wid] = s1; dred[8 + wid] = s2; }
        __syncthreads();
        if (tid == 0) {
            double S1 = 0.0, S2 = 0.0;
            #pragma unroll
            for (int w2 = 0; w2 < 8; ++w2) { S1 += dred[w2]; S2 += dred[8 + w2]; }
            dpart[mb * 2 + 0] = S1;
            dpart[mb * 2 + 1] = S2;
        }
    }
    __syncthreads();

    // ---------------- tail 2: global last block finalizes ------------------
    __threadfence();
    if (tid == 0)
        s_f2 = __hip_atomic_fetch_add(gcnt, 1, __ATOMIC_ACQ_REL, __HIP_MEMORY_SCOPE_AGENT);
    __syncthreads();
    if (s_f2 != NB_M - 1) return;

    double f1 = 0.0, f2 = 0.0;
    if (tid < NB_M) { f1 = dpart[tid * 2]; f2 = dpart[tid * 2 + 1]; }

    double wm2 = 0.0, tcd = 0.0, wls = 0.0, offs = 0.0;
    for (int i = tid; i < K_DIM; i += 512) {
        float w = Wm[i];
        wm2 += (double)w * (double)w;
        float ld = Wld[i];
        tcd += exp(2.0 * (double)ld);
        wls += (double)ld;
    }
    for (int i = tid; i < 1024; i += 512) offs += (double)misc[i];

    {
        double* dred = (double*)&As[0][0];
        double vals[6] = {f1, f2, wm2, tcd, wls, offs};
        __syncthreads();
        #pragma unroll
        for (int s = 0; s < 6; ++s) {
            double v = vals[s];
            #pragma unroll
            for (int off = 32; off; off >>= 1) v += __shfl_down(v, off);
            if (lane == 0) dred[s * 8 + wid] = v;
        }
        __syncthreads();
        if (tid == 0) {
            double a6[6];
            #pragma unroll
            for (int s = 0; s < 6; ++s) {
                double v = 0.0;
                #pragma unroll
                for (int w2 = 0; w2 < 8; ++w2) v += dred[s * 8 + w2];
                a6[s] = v;
            }
            double trace_cov = a6[5] + a6[3];                 // sum(L*L)
            double kl = 0.5 * (a6[2] + trace_cov - 2.0 * a6[4]);
            double wish = 1.5 * (-2.0 * (double)nld) - 0.005 * (double)nprec;
            double elbo = a6[1] / a6[0] + 1e-4 * (wish - kl);
            out[0] = (float)(-elbo);
        }
    }
}
#undef BAR
#undef WAITL

// ---------------------------------------------------------------------------
extern "C" void kernel_launch(void* const* d_in, const int* in_sizes, int n_in,
                              void* d_out, int out_size, void* d_ws, size_t ws_size,
                              hipStream_t stream) {
    const float* x    = (const float*)d_in[0];
    const float* y    = (const float*)d_in[1];
    const float* cnt  = (const float*)d_in[2];
    // d_in[3] = noise_mean (unused by the reference math)
    const float* nld  = (const float*)d_in[4];
    const float* Wm   = (const float*)d_in[5];
    const float* Wld  = (const float*)d_in[6];
    const float* Woff = (const float*)d_in[7];

    char* ws = (char*)d_ws;
    unsigned char* Xq = (unsigned char*)(ws);              // 33554432 B
    unsigned char* Lq = (unsigned char*)(ws + 33554432);   // 4194304 B
    double* dpart  = (double*)(ws + 40000000);             // 1024 B
    int*    mbcnt  = (int*)(ws + 40008192);                // 256 B
    int*    gcnt   = (int*)(ws + 40008448);                // 4 B
    float*  U      = (float*)(ws + 75497472);              // 64 KB
    float*  qpart  = (float*)(ws + 75563008);              // 512 KB
    float*  misc   = (float*)(ws + 76611584);              // 4 KB
    float*  outp   = (float*)d_out;

    hipMemsetAsync(ws + 40008192, 0, 512, stream);   // zero mbcnt + gcnt

    prep_fused<<<dim3(1024 + M_DIM), 256, 0, stream>>>(x, Wm, Woff, Wld, Xq, Lq, U, misc);
    quad_all<<<dim3(NB_M, 4), 512, 0, stream>>>(Xq, Lq, qpart, y, cnt, nld, U,
                                                Wm, Wld, misc, dpart, mbcnt, gcnt, outp);
}

// Round 17
// 91.927 us; speedup vs baseline: 4.3736x; 1.4374x over previous
//
#include <hip/hip_runtime.h>
#include <hip/hip_bf16.h>
#include <math.h>

#define LOG2PI_F 1.8378770664093453f

typedef int i32x4 __attribute__((ext_vector_type(4)));
typedef int i32x8 __attribute__((ext_vector_type(8)));
typedef float f32x4 __attribute__((ext_vector_type(4)));

#define M_DIM 16384
#define K_DIM 2048
#define N_DIM 2048
#define BM 256
#define BN 256
#define BK 128
#define NB_N (N_DIM / BN) /* 8 */
#define NB_M (M_DIM / BM) /* 64 */
#define LSCALE 256.0f
#define QDESCALE (1.0f / 65536.0f)
#define SCALE_ONE 0x7F7F7F7F   /* e8m0 biased 127 = 2^0 in all byte lanes */

// async global->LDS, 16B per lane. LDS dest is wave-uniform base + lane*16.
__device__ __forceinline__ void gload16(const void* g, void* l) {
    __builtin_amdgcn_global_load_lds(
        (__attribute__((address_space(1))) void*)g,
        (__attribute__((address_space(3))) void*)l, 16, 0, 0);
}

// pack 4 floats -> 4 e4m3 bytes (HW RNE+sat, OCP on gfx950)
__device__ __forceinline__ unsigned int pk4_fp8(float a, float b, float c, float d) {
    unsigned int w = (unsigned int)__builtin_amdgcn_cvt_pk_fp8_f32(a, b, 0, false);
    w = (unsigned int)__builtin_amdgcn_cvt_pk_fp8_f32(c, d, (int)w, true);
    return w;
}

// ---------------------------------------------------------------------------
// prep_fused (R14, measured good): blocks [0,1024) build Lq (fp8 L^T, x256)
// + Woff^2 partials; blocks [1024,1024+16384) cast X->fp8 + pred_mean GEMV.
// ---------------------------------------------------------------------------
__global__ __launch_bounds__(256) void prep_fused(const float* __restrict__ X,
                                                  const float* __restrict__ Wm,
                                                  const float* __restrict__ Woff,
                                                  const float* __restrict__ Wld,
                                                  unsigned char* __restrict__ Xq,
                                                  unsigned char* __restrict__ Lq,
                                                  float* __restrict__ U,
                                                  float* __restrict__ misc_arr) {
    __shared__ float tile[64][65];
    __shared__ float red[4];
    const int bid = blockIdx.x;
    const int tid = threadIdx.x;

    if (bid < 1024) {
        const int jt = (bid & 31) * 64;
        const int it = (bid >> 5) * 64;
        float ss = 0.f;
        if (it + 63 >= jt) {
            for (int e = tid; e < 4096; e += 256) {
                int r = e >> 6, c = e & 63;
                tile[r][c] = Woff[(size_t)(it + r) * K_DIM + (jt + c)];
            }
        }
        __syncthreads();
        for (int e = tid; e < 4096; e += 256) {
            int jr = e >> 6, ic = e & 63;
            int i = it + ic, j = jt + jr;
            float v = 0.f;
            if (i > j) { v = tile[ic][jr]; ss += v * v; }
            else if (i == j) v = expf(Wld[i]);
            unsigned int w = (unsigned int)__builtin_amdgcn_cvt_pk_fp8_f32(v * LSCALE, 0.f, 0, false);
            Lq[(size_t)j * K_DIM + i] = (unsigned char)(w & 0xffu);
        }
        #pragma unroll
        for (int off = 32; off; off >>= 1) ss += __shfl_down(ss, off);
        if ((tid & 63) == 0) red[tid >> 6] = ss;
        __syncthreads();
        if (tid == 0) misc_arr[bid] = red[0] + red[1] + red[2] + red[3];
    } else {
        const int b = bid - 1024;
        const float* xr = X + (size_t)b * K_DIM;
        unsigned char* xo = Xq + (size_t)b * K_DIM;
        const int base = tid * 8;
        float4 v0 = *(const float4*)(xr + base);
        float4 v1 = *(const float4*)(xr + base + 4);
        float4 w0 = *(const float4*)(Wm + base);
        float4 w1 = *(const float4*)(Wm + base + 4);
        float dot = v0.x * w0.x + v0.y * w0.y + v0.z * w0.z + v0.w * w0.w
                  + v1.x * w1.x + v1.y * w1.y + v1.z * w1.z + v1.w * w1.w;
        uint2 p;
        p.x = pk4_fp8(v0.x, v0.y, v0.z, v0.w);
        p.y = pk4_fp8(v1.x, v1.y, v1.z, v1.w);
        *(uint2*)(xo + base) = p;
        #pragma unroll
        for (int off = 32; off; off >>= 1) dot += __shfl_down(dot, off);
        if ((tid & 63) == 0) red[tid >> 6] = dot;
        __syncthreads();
        if (tid == 0) U[b] = red[0] + red[1] + red[2] + red[3];
    }
}

// ---------------------------------------------------------------------------
// quad_gemm fp8 MX 256x256, BK=128, 2-buf LDS (128 KB), 8 waves (2M x 4N).
// (EXACT R12/R14 kernel -- measured best; no tail, no fences, no atomics.)
// ---------------------------------------------------------------------------
__device__ __forceinline__ i32x8 frag128(const unsigned char* base, int roff, int g) {
    const unsigned char* rb = base + roff * 128;
    int x = (roff & 7) << 4;
    i32x4 lo = *(const i32x4*)(rb + (((g * 2) << 4) ^ x));
    i32x4 hi = *(const i32x4*)(rb + (((g * 2 + 1) << 4) ^ x));
    return __builtin_shufflevector(lo, hi, 0, 1, 2, 3, 4, 5, 6, 7);
}

#define MXMFMA(A, B, C) __builtin_amdgcn_mfma_scale_f32_16x16x128_f8f6f4( \
        (A), (B), (C), 0, 0, 0, SCALE_ONE, 0, SCALE_ONE)
#define BAR() asm volatile("s_barrier" ::: "memory")
#define WAITL() { asm volatile("s_waitcnt lgkmcnt(0)" ::: "memory"); \
                  __builtin_amdgcn_sched_barrier(0); }

__global__ __launch_bounds__(512, 2) void quad_gemm(const unsigned char* __restrict__ Xq,
                                                    const unsigned char* __restrict__ Lq,
                                                    float* __restrict__ qpart) {
    __shared__ unsigned char As[2][BM * BK];   // 2 x 32 KB
    __shared__ unsigned char Bs[2][BN * BK];   // 2 x 32 KB (128 KB total)

    const int mb = blockIdx.x;
    const int jp = blockIdx.y;              // 0..3
    const int tid = threadIdx.x;
    const int lane = tid & 63;
    const int wid = tid >> 6;               // 0..7
    const int wr = wid >> 2, wc = wid & 3;  // 2M x 4N wave grid
    const int g = lane >> 4, r16 = lane & 15;
    const int brow = mb * BM;
    const int srow = lane >> 3;             // 0..7 == (lds row & 7)
    const int scol = (lane & 7) ^ srow;     // pre-swizzled 16B source chunk

    auto gemm_one = [&](int nb) {
        const int bcol = nb * BN;
        const int NT = (K_DIM - bcol) >> 7;   // 16 - 2*nb, in [2,16]

        const unsigned char* pA[2];
        const unsigned char* pB[2];
        #pragma unroll
        for (int h = 0; h < 2; ++h) {
            pA[h] = Xq + (size_t)(brow + h * 128 + wid * 16 + srow) * K_DIM + bcol + scol * 16;
            pB[h] = Lq + (size_t)(bcol + h * 128 + wid * 16 + srow) * K_DIM + bcol + scol * 16;
        }
        auto stgA = [&](int t, int h, int buf) {
            const unsigned char* s = pA[h] + (size_t)t * 128;
            char* d = (char*)As[buf] + h * 16384 + wid * 2048;
            gload16(s, d);
            gload16(s + (size_t)8 * K_DIM, d + 1024);
        };
        auto stgB = [&](int t, int h, int buf) {
            const unsigned char* s = pB[h] + (size_t)t * 128;
            char* d = (char*)Bs[buf] + h * 16384 + wid * 2048;
            gload16(s, d);
            gload16(s + (size_t)8 * K_DIM, d + 1024);
        };

        f32x4 acc[8][4];
        const f32x4 zero = {0.f, 0.f, 0.f, 0.f};
        #pragma unroll
        for (int m = 0; m < 8; ++m)
            #pragma unroll
            for (int n = 0; n < 4; ++n) acc[m][n] = zero;

        stgA(0, 0, 0); stgA(0, 1, 0); stgB(0, 0, 0); stgB(0, 1, 0);
        stgB(1, 0, 1); stgB(1, 1, 1);
        asm volatile("s_waitcnt vmcnt(4)" ::: "memory");
        BAR();

        for (int t = 0; t < NT; ++t) {
            const int cur = t & 1, nbuf = cur ^ 1;
            const unsigned char* Abase = As[cur] + wr * 16384;
            const unsigned char* Bbase = Bs[cur] + (wc >> 1) * 16384;
            const int brow2 = (wc & 1) * 64;
            const bool s1 = (t + 1 < NT), s2 = (t + 2 < NT);
            i32x8 bf[4], af[4];

            #pragma unroll
            for (int n = 0; n < 4; ++n) bf[n] = frag128(Bbase, brow2 + n * 16 + r16, g);
            #pragma unroll
            for (int m = 0; m < 4; ++m) af[m] = frag128(Abase, m * 16 + r16, g);
            if (s1) { stgA(t + 1, 0, nbuf); stgA(t + 1, 1, nbuf); }
            BAR();
            WAITL();
            __builtin_amdgcn_s_setprio(1);
            #pragma unroll
            for (int m = 0; m < 4; ++m)
                #pragma unroll
                for (int n = 0; n < 4; ++n)
                    acc[m][n] = MXMFMA(af[m], bf[n], acc[m][n]);
            __builtin_amdgcn_s_setprio(0);
            BAR();

            #pragma unroll
            for (int m = 0; m < 4; ++m) af[m] = frag128(Abase, 64 + m * 16 + r16, g);
            if (s2) { stgB(t + 2, 0, cur); stgB(t + 2, 1, cur); }
            BAR();
            WAITL();
            __builtin_amdgcn_s_setprio(1);
            #pragma unroll
            for (int m = 0; m < 4; ++m)
                #pragma unroll
                for (int n = 0; n < 4; ++n)
                    acc[4 + m][n] = MXMFMA(af[m], bf[n], acc[4 + m][n]);
            __builtin_amdgcn_s_setprio(0);

            if (s2)      asm volatile("s_waitcnt vmcnt(4)" ::: "memory");
            else if (s1) asm volatile("s_waitcnt vmcnt(0)" ::: "memory");
            BAR();
        }

        float* qbuf = (float*)&As[0][0];
        __syncthreads();
        #pragma unroll
        for (int m = 0; m < 8; ++m) {
            #pragma unroll
            for (int r = 0; r < 4; ++r) {
                float s = 0.f;
                #pragma unroll
                for (int n = 0; n < 4; ++n) {
                    float t2 = acc[m][n][r];
                    s += t2 * t2;
                }
                #pragma unroll
                for (int off = 1; off < 16; off <<= 1) s += __shfl_xor(s, off);
                if (r16 == 0) qbuf[wc * 256 + wr * 128 + m * 16 + g * 4 + r] = s;
            }
        }
        __syncthreads();
        if (tid < BM)
            qpart[(size_t)(brow + tid) * NB_N + nb] =
                (qbuf[tid] + qbuf[256 + tid] + qbuf[512 + tid] + qbuf[768 + tid]) * QDESCALE;
        __syncthreads();
    };

    gemm_one(jp);        // heavy: NT = 16 - 2*jp
    gemm_one(7 - jp);    // light: NT = 2 + 2*jp; sum = 18 always
}
#undef BAR
#undef WAITL

// ---------------------------------------------------------------------------
// tail_all: single block, 1024 threads. Replaces row_part + finalize2
// (removes one launch boundary). Each thread strides 16 rows; qpart
// (704 KB with Y/Cnt/U) is L2-resident after quad_gemm.
// ---------------------------------------------------------------------------
__global__ __launch_bounds__(1024) void tail_all(const float* __restrict__ Y,
                                                 const float* __restrict__ Cnt,
                                                 const float* __restrict__ nld_p,
                                                 const float* __restrict__ U,
                                                 const float* __restrict__ qpart,
                                                 const float* __restrict__ Wm,
                                                 const float* __restrict__ Wld,
                                                 const float* __restrict__ misc_arr,
                                                 float* __restrict__ out) {
    const int tid = threadIdx.x;
    const int lane = tid & 63;
    const int wid = tid >> 6;           // 0..15
    const float nld = nld_p[0];
    const float inv_sig = expf(-nld);
    const float nprec = inv_sig * inv_sig;

    double s1 = 0.0, s2 = 0.0;
    for (int b = tid; b < M_DIM; b += 1024) {
        const float4* qp = (const float4*)(qpart + (size_t)b * NB_N);
        float4 q0 = qp[0], q1 = qp[1];
        float q = q0.x + q0.y + q0.z + q0.w + q1.x + q1.y + q1.z + q1.w;
        float c = Cnt[b];
        float d = (Y[b] - U[b]) * inv_sig;
        float pl = -0.5f * d * d - nld - 0.5f * LOG2PI_F;
        float tt = 0.5f * q * c * c * nprec;
        s1 += (double)c;
        s2 += (double)((pl - tt) * c);
    }

    double wm2 = 0.0, tcd = 0.0, wls = 0.0, offs = 0.0;
    for (int i = tid; i < K_DIM; i += 1024) {
        float w = Wm[i];
        wm2 += (double)w * (double)w;
        float ld = Wld[i];
        tcd += exp(2.0 * (double)ld);
        wls += (double)ld;
    }
    if (tid < 1024 && tid < 1024) {
        // misc has 1024 entries; one per thread
        offs = (double)misc_arr[tid];
    }

    __shared__ double red[6][16];
    double vals[6] = {s1, s2, wm2, tcd, wls, offs};
    #pragma unroll
    for (int s = 0; s < 6; ++s) {
        double v = vals[s];
        #pragma unroll
        for (int off = 32; off; off >>= 1) v += __shfl_down(v, off);
        if (lane == 0) red[s][wid] = v;
    }
    __syncthreads();
    if (tid == 0) {
        double a6[6];
        #pragma unroll
        for (int s = 0; s < 6; ++s) {
            double v = 0.0;
            #pragma unroll
            for (int w2 = 0; w2 < 16; ++w2) v += red[s][w2];
            a6[s] = v;
        }
        double trace_cov = a6[5] + a6[3];                  // sum(L*L)
        double kl = 0.5 * (a6[2] + trace_cov - 2.0 * a6[4]); // prior_scale=1
        double wish = 1.5 * (-2.0 * (double)nld) - 0.005 * (double)nprec;
        double elbo = a6[1] / a6[0] + 1e-4 * (wish - kl);
        out[0] = (float)(-elbo);
    }
}

// ---------------------------------------------------------------------------
extern "C" void kernel_launch(void* const* d_in, const int* in_sizes, int n_in,
                              void* d_out, int out_size, void* d_ws, size_t ws_size,
                              hipStream_t stream) {
    const float* x    = (const float*)d_in[0];
    const float* y    = (const float*)d_in[1];
    const float* cnt  = (const float*)d_in[2];
    // d_in[3] = noise_mean (unused by the reference math)
    const float* nld  = (const float*)d_in[4];
    const float* Wm   = (const float*)d_in[5];
    const float* Wld  = (const float*)d_in[6];
    const float* Woff = (const float*)d_in[7];

    char* ws = (char*)d_ws;
    unsigned char* Xq = (unsigned char*)(ws);              // 33554432 B
    unsigned char* Lq = (unsigned char*)(ws + 33554432);   // 4194304 B
    float*  U      = (float*)(ws + 75497472);              // 64 KB
    float*  qpart  = (float*)(ws + 75563008);              // 512 KB
    float*  misc   = (float*)(ws + 76611584);              // 4 KB

    prep_fused<<<dim3(1024 + M_DIM), 256, 0, stream>>>(x, Wm, Woff, Wld, Xq, Lq, U, misc);
    quad_gemm<<<dim3(NB_M, 4), 512, 0, stream>>>(Xq, Lq, qpart);
    tail_all<<<1, 1024, 0, stream>>>(y, cnt, nld, U, qpart, Wm, Wld, misc, (float*)d_out);
}

// Round 18
// 87.676 us; speedup vs baseline: 4.5857x; 1.0485x over previous
//
#include <hip/hip_runtime.h>
#include <hip/hip_bf16.h>
#include <math.h>

#define LOG2PI_F 1.8378770664093453f

typedef int i32x4 __attribute__((ext_vector_type(4)));
typedef int i32x8 __attribute__((ext_vector_type(8)));
typedef float f32x4 __attribute__((ext_vector_type(4)));

#define M_DIM 16384
#define K_DIM 2048
#define N_DIM 2048
#define BM 256
#define BN 256
#define BK 128
#define NB_N (N_DIM / BN) /* 8 */
#define NB_M (M_DIM / BM) /* 64 */
#define LSCALE 256.0f
#define QDESCALE (1.0f / 65536.0f)
#define SCALE_ONE 0x7F7F7F7F   /* e8m0 biased 127 = 2^0 in all byte lanes */

// async global->LDS, 16B per lane. LDS dest is wave-uniform base + lane*16.
__device__ __forceinline__ void gload16(const void* g, void* l) {
    __builtin_amdgcn_global_load_lds(
        (__attribute__((address_space(1))) void*)g,
        (__attribute__((address_space(3))) void*)l, 16, 0, 0);
}

// pack 4 floats -> 4 e4m3 bytes (HW RNE+sat, OCP on gfx950)
__device__ __forceinline__ unsigned int pk4_fp8(float a, float b, float c, float d) {
    unsigned int w = (unsigned int)__builtin_amdgcn_cvt_pk_fp8_f32(a, b, 0, false);
    w = (unsigned int)__builtin_amdgcn_cvt_pk_fp8_f32(c, d, (int)w, true);
    return w;
}

// ---------------------------------------------------------------------------
// prep_fused (R14, measured good): blocks [0,1024) build Lq (fp8 L^T, x256)
// + Woff^2 partials; blocks [1024,1024+16384) cast X->fp8 + pred_mean GEMV.
// ---------------------------------------------------------------------------
__global__ __launch_bounds__(256) void prep_fused(const float* __restrict__ X,
                                                  const float* __restrict__ Wm,
                                                  const float* __restrict__ Woff,
                                                  const float* __restrict__ Wld,
                                                  unsigned char* __restrict__ Xq,
                                                  unsigned char* __restrict__ Lq,
                                                  float* __restrict__ U,
                                                  float* __restrict__ misc_arr) {
    __shared__ float tile[64][65];
    __shared__ float red[4];
    const int bid = blockIdx.x;
    const int tid = threadIdx.x;

    if (bid < 1024) {
        const int jt = (bid & 31) * 64;
        const int it = (bid >> 5) * 64;
        float ss = 0.f;
        if (it + 63 >= jt) {
            for (int e = tid; e < 4096; e += 256) {
                int r = e >> 6, c = e & 63;
                tile[r][c] = Woff[(size_t)(it + r) * K_DIM + (jt + c)];
            }
        }
        __syncthreads();
        for (int e = tid; e < 4096; e += 256) {
            int jr = e >> 6, ic = e & 63;
            int i = it + ic, j = jt + jr;
            float v = 0.f;
            if (i > j) { v = tile[ic][jr]; ss += v * v; }
            else if (i == j) v = expf(Wld[i]);
            unsigned int w = (unsigned int)__builtin_amdgcn_cvt_pk_fp8_f32(v * LSCALE, 0.f, 0, false);
            Lq[(size_t)j * K_DIM + i] = (unsigned char)(w & 0xffu);
        }
        #pragma unroll
        for (int off = 32; off; off >>= 1) ss += __shfl_down(ss, off);
        if ((tid & 63) == 0) red[tid >> 6] = ss;
        __syncthreads();
        if (tid == 0) misc_arr[bid] = red[0] + red[1] + red[2] + red[3];
    } else {
        const int b = bid - 1024;
        const float* xr = X + (size_t)b * K_DIM;
        unsigned char* xo = Xq + (size_t)b * K_DIM;
        const int base = tid * 8;
        float4 v0 = *(const float4*)(xr + base);
        float4 v1 = *(const float4*)(xr + base + 4);
        float4 w0 = *(const float4*)(Wm + base);
        float4 w1 = *(const float4*)(Wm + base + 4);
        float dot = v0.x * w0.x + v0.y * w0.y + v0.z * w0.z + v0.w * w0.w
                  + v1.x * w1.x + v1.y * w1.y + v1.z * w1.z + v1.w * w1.w;
        uint2 p;
        p.x = pk4_fp8(v0.x, v0.y, v0.z, v0.w);
        p.y = pk4_fp8(v1.x, v1.y, v1.z, v1.w);
        *(uint2*)(xo + base) = p;
        #pragma unroll
        for (int off = 32; off; off >>= 1) dot += __shfl_down(dot, off);
        if ((tid & 63) == 0) red[tid >> 6] = dot;
        __syncthreads();
        if (tid == 0) U[b] = red[0] + red[1] + red[2] + red[3];
    }
}

// ---------------------------------------------------------------------------
// quad_gemm fp8 MX 256x256, BK=128, 2-buf LDS (128 KB), 8 waves (2M x 4N).
// (EXACT R12/R14 kernel -- measured best.)
// ---------------------------------------------------------------------------
__device__ __forceinline__ i32x8 frag128(const unsigned char* base, int roff, int g) {
    const unsigned char* rb = base + roff * 128;
    int x = (roff & 7) << 4;
    i32x4 lo = *(const i32x4*)(rb + (((g * 2) << 4) ^ x));
    i32x4 hi = *(const i32x4*)(rb + (((g * 2 + 1) << 4) ^ x));
    return __builtin_shufflevector(lo, hi, 0, 1, 2, 3, 4, 5, 6, 7);
}

#define MXMFMA(A, B, C) __builtin_amdgcn_mfma_scale_f32_16x16x128_f8f6f4( \
        (A), (B), (C), 0, 0, 0, SCALE_ONE, 0, SCALE_ONE)
#define BAR() asm volatile("s_barrier" ::: "memory")
#define WAITL() { asm volatile("s_waitcnt lgkmcnt(0)" ::: "memory"); \
                  __builtin_amdgcn_sched_barrier(0); }

__global__ __launch_bounds__(512, 2) void quad_gemm(const unsigned char* __restrict__ Xq,
                                                    const unsigned char* __restrict__ Lq,
                                                    float* __restrict__ qpart) {
    __shared__ unsigned char As[2][BM * BK];   // 2 x 32 KB
    __shared__ unsigned char Bs[2][BN * BK];   // 2 x 32 KB (128 KB total)

    const int mb = blockIdx.x;
    const int jp = blockIdx.y;              // 0..3
    const int tid = threadIdx.x;
    const int lane = tid & 63;
    const int wid = tid >> 6;               // 0..7
    const int wr = wid >> 2, wc = wid & 3;  // 2M x 4N wave grid
    const int g = lane >> 4, r16 = lane & 15;
    const int brow = mb * BM;
    const int srow = lane >> 3;             // 0..7 == (lds row & 7)
    const int scol = (lane & 7) ^ srow;     // pre-swizzled 16B source chunk

    auto gemm_one = [&](int nb) {
        const int bcol = nb * BN;
        const int NT = (K_DIM - bcol) >> 7;   // 16 - 2*nb, in [2,16]

        const unsigned char* pA[2];
        const unsigned char* pB[2];
        #pragma unroll
        for (int h = 0; h < 2; ++h) {
            pA[h] = Xq + (size_t)(brow + h * 128 + wid * 16 + srow) * K_DIM + bcol + scol * 16;
            pB[h] = Lq + (size_t)(bcol + h * 128 + wid * 16 + srow) * K_DIM + bcol + scol * 16;
        }
        auto stgA = [&](int t, int h, int buf) {
            const unsigned char* s = pA[h] + (size_t)t * 128;
            char* d = (char*)As[buf] + h * 16384 + wid * 2048;
            gload16(s, d);
            gload16(s + (size_t)8 * K_DIM, d + 1024);
        };
        auto stgB = [&](int t, int h, int buf) {
            const unsigned char* s = pB[h] + (size_t)t * 128;
            char* d = (char*)Bs[buf] + h * 16384 + wid * 2048;
            gload16(s, d);
            gload16(s + (size_t)8 * K_DIM, d + 1024);
        };

        f32x4 acc[8][4];
        const f32x4 zero = {0.f, 0.f, 0.f, 0.f};
        #pragma unroll
        for (int m = 0; m < 8; ++m)
            #pragma unroll
            for (int n = 0; n < 4; ++n) acc[m][n] = zero;

        stgA(0, 0, 0); stgA(0, 1, 0); stgB(0, 0, 0); stgB(0, 1, 0);
        stgB(1, 0, 1); stgB(1, 1, 1);
        asm volatile("s_waitcnt vmcnt(4)" ::: "memory");
        BAR();

        for (int t = 0; t < NT; ++t) {
            const int cur = t & 1, nbuf = cur ^ 1;
            const unsigned char* Abase = As[cur] + wr * 16384;
            const unsigned char* Bbase = Bs[cur] + (wc >> 1) * 16384;
            const int brow2 = (wc & 1) * 64;
            const bool s1 = (t + 1 < NT), s2 = (t + 2 < NT);
            i32x8 bf[4], af[4];

            #pragma unroll
            for (int n = 0; n < 4; ++n) bf[n] = frag128(Bbase, brow2 + n * 16 + r16, g);
            #pragma unroll
            for (int m = 0; m < 4; ++m) af[m] = frag128(Abase, m * 16 + r16, g);
            if (s1) { stgA(t + 1, 0, nbuf); stgA(t + 1, 1, nbuf); }
            BAR();
            WAITL();
            __builtin_amdgcn_s_setprio(1);
            #pragma unroll
            for (int m = 0; m < 4; ++m)
                #pragma unroll
                for (int n = 0; n < 4; ++n)
                    acc[m][n] = MXMFMA(af[m], bf[n], acc[m][n]);
            __builtin_amdgcn_s_setprio(0);
            BAR();

            #pragma unroll
            for (int m = 0; m < 4; ++m) af[m] = frag128(Abase, 64 + m * 16 + r16, g);
            if (s2) { stgB(t + 2, 0, cur); stgB(t + 2, 1, cur); }
            BAR();
            WAITL();
            __builtin_amdgcn_s_setprio(1);
            #pragma unroll
            for (int m = 0; m < 4; ++m)
                #pragma unroll
                for (int n = 0; n < 4; ++n)
                    acc[4 + m][n] = MXMFMA(af[m], bf[n], acc[4 + m][n]);
            __builtin_amdgcn_s_setprio(0);

            if (s2)      asm volatile("s_waitcnt vmcnt(4)" ::: "memory");
            else if (s1) asm volatile("s_waitcnt vmcnt(0)" ::: "memory");
            BAR();
        }

        float* qbuf = (float*)&As[0][0];
        __syncthreads();
        #pragma unroll
        for (int m = 0; m < 8; ++m) {
            #pragma unroll
            for (int r = 0; r < 4; ++r) {
                float s = 0.f;
                #pragma unroll
                for (int n = 0; n < 4; ++n) {
                    float t2 = acc[m][n][r];
                    s += t2 * t2;
                }
                #pragma unroll
                for (int off = 1; off < 16; off <<= 1) s += __shfl_xor(s, off);
                if (r16 == 0) qbuf[wc * 256 + wr * 128 + m * 16 + g * 4 + r] = s;
            }
        }
        __syncthreads();
        if (tid < BM)
            qpart[(size_t)(brow + tid) * NB_N + nb] =
                (qbuf[tid] + qbuf[256 + tid] + qbuf[512 + tid] + qbuf[768 + tid]) * QDESCALE;
        __syncthreads();
    };

    gemm_one(jp);        // heavy: NT = 16 - 2*jp
    gemm_one(7 - jp);    // light: NT = 2 + 2*jp; sum = 18 always
}
#undef BAR
#undef WAITL

// ---------------------------------------------------------------------------
// row_part: 128 blocks x 256 threads, 128 rows each (XCD-spread qpart read).
// ---------------------------------------------------------------------------
__global__ __launch_bounds__(256) void row_part(const float* __restrict__ Y,
                                                const float* __restrict__ Cnt,
                                                const float* __restrict__ nld_p,
                                                const float* __restrict__ U,
                                                const float* __restrict__ qpart,
                                                double* __restrict__ dpart) {
    const int tid = threadIdx.x;
    const float nld = nld_p[0];
    const float inv_sig = expf(-nld);
    const float nprec = inv_sig * inv_sig;
    double s1 = 0.0, s2 = 0.0;
    if (tid < 128) {
        const int b = blockIdx.x * 128 + tid;
        float c = Cnt[b];
        const float4* qp = (const float4*)(qpart + (size_t)b * NB_N);
        float4 q0 = qp[0], q1 = qp[1];
        float q = q0.x + q0.y + q0.z + q0.w + q1.x + q1.y + q1.z + q1.w;
        float d = (Y[b] - U[b]) * inv_sig;
        float pl = -0.5f * d * d - nld - 0.5f * LOG2PI_F;
        float tt = 0.5f * q * c * c * nprec;
        s1 = (double)c;
        s2 = (double)((pl - tt) * c);
    }
    __shared__ double red[2][4];
    #pragma unroll
    for (int off = 32; off; off >>= 1) {
        s1 += __shfl_down(s1, off);
        s2 += __shfl_down(s2, off);
    }
    if ((tid & 63) == 0) { red[0][tid >> 6] = s1; red[1][tid >> 6] = s2; }
    __syncthreads();
    if (tid == 0) {
        dpart[blockIdx.x * 2 + 0] = red[0][0] + red[0][1] + red[0][2] + red[0][3];
        dpart[blockIdx.x * 2 + 1] = red[1][0] + red[1][1] + red[1][2] + red[1][3];
    }
}

// ---------------------------------------------------------------------------
// finalize2: combine 128 partials + KL/wishart scalar terms. One block.
// ---------------------------------------------------------------------------
__global__ __launch_bounds__(256) void finalize2(const float* __restrict__ nld_p,
                                                 const float* __restrict__ Wm,
                                                 const float* __restrict__ Wld,
                                                 const double* __restrict__ dpart,
                                                 const float* __restrict__ misc_arr,
                                                 float* __restrict__ out) {
    const int tid = threadIdx.x;
    const float nld = nld_p[0];
    const float inv_sig = expf(-nld);
    const float nprec = inv_sig * inv_sig;

    double s1 = 0.0, s2 = 0.0;
    if (tid < 128) { s1 = dpart[tid * 2]; s2 = dpart[tid * 2 + 1]; }

    double wm2 = 0.0, tcd = 0.0, wls = 0.0, offs = 0.0;
    for (int i = tid; i < K_DIM; i += 256) {
        float w = Wm[i];
        wm2 += (double)w * (double)w;
        float ld = Wld[i];
        tcd += exp(2.0 * (double)ld);
        wls += (double)ld;
    }
    for (int i = tid; i < 1024; i += 256) offs += (double)misc_arr[i];

    __shared__ double red[6][4];
    double vals[6] = {s1, s2, wm2, tcd, wls, offs};
    #pragma unroll
    for (int s = 0; s < 6; ++s) {
        double v = vals[s];
        #pragma unroll
        for (int off = 32; off; off >>= 1) v += __shfl_down(v, off);
        if ((tid & 63) == 0) red[s][tid >> 6] = v;
    }
    __syncthreads();
    if (tid == 0) {
        double S1 = red[0][0] + red[0][1] + red[0][2] + red[0][3];
        double S2 = red[1][0] + red[1][1] + red[1][2] + red[1][3];
        double MSE = red[2][0] + red[2][1] + red[2][2] + red[2][3];
        double TCD = red[3][0] + red[3][1] + red[3][2] + red[3][3];
        double WLS = red[4][0] + red[4][1] + red[4][2] + red[4][3];
        double OFFS = red[5][0] + red[5][1] + red[5][2] + red[5][3];
        double trace_cov = OFFS + TCD;
        double kl = 0.5 * (MSE + trace_cov - 2.0 * WLS);
        double wish = 1.5 * (-2.0 * (double)nld) - 0.005 * (double)nprec;
        double elbo = S2 / S1 + 1e-4 * (wish - kl);
        out[0] = (float)(-elbo);
    }
}

// ---------------------------------------------------------------------------
extern "C" void kernel_launch(void* const* d_in, const int* in_sizes, int n_in,
                              void* d_out, int out_size, void* d_ws, size_t ws_size,
                              hipStream_t stream) {
    const float* x    = (const float*)d_in[0];
    const float* y    = (const float*)d_in[1];
    const float* cnt  = (const float*)d_in[2];
    // d_in[3] = noise_mean (unused by the reference math)
    const float* nld  = (const float*)d_in[4];
    const float* Wm   = (const float*)d_in[5];
    const float* Wld  = (const float*)d_in[6];
    const float* Woff = (const float*)d_in[7];

    char* ws = (char*)d_ws;
    unsigned char* Xq = (unsigned char*)(ws);              // 33554432 B
    unsigned char* Lq = (unsigned char*)(ws + 33554432);   // 4194304 B
    double* dpart  = (double*)(ws + 40000000);             // 2048 B
    float*  U      = (float*)(ws + 75497472);              // 64 KB
    float*  qpart  = (float*)(ws + 75563008);              // 512 KB
    float*  misc   = (float*)(ws + 76611584);              // 4 KB

    prep_fused<<<dim3(1024 + M_DIM), 256, 0, stream>>>(x, Wm, Woff, Wld, Xq, Lq, U, misc);
    quad_gemm<<<dim3(NB_M, 4), 512, 0, stream>>>(Xq, Lq, qpart);
    row_part<<<dim3(128), 256, 0, stream>>>(y, cnt, nld, U, qpart, dpart);
    finalize2<<<1, 256, 0, stream>>>(nld, Wm, Wld, dpart, misc, (float*)d_out);
}

// Round 19
// 86.218 us; speedup vs baseline: 4.6633x; 1.0169x over previous
//
#include <hip/hip_runtime.h>
#include <hip/hip_bf16.h>
#include <math.h>

#define LOG2PI_F 1.8378770664093453f

typedef int i32x4 __attribute__((ext_vector_type(4)));
typedef int i32x8 __attribute__((ext_vector_type(8)));
typedef float f32x4 __attribute__((ext_vector_type(4)));

#define M_DIM 16384
#define K_DIM 2048
#define N_DIM 2048
#define BM 256
#define BN 256
#define BK 128
#define NB_N (N_DIM / BN) /* 8 */
#define NB_M (M_DIM / BM) /* 64 */
#define LSCALE 256.0f
#define QDESCALE (1.0f / 65536.0f)
#define SCALE_ONE 0x7F7F7F7F   /* e8m0 biased 127 = 2^0 in all byte lanes */

// async global->LDS, 16B per lane. LDS dest is wave-uniform base + lane*16.
__device__ __forceinline__ void gload16(const void* g, void* l) {
    __builtin_amdgcn_global_load_lds(
        (__attribute__((address_space(1))) void*)g,
        (__attribute__((address_space(3))) void*)l, 16, 0, 0);
}

// pack 4 floats -> 4 e4m3 bytes (HW RNE+sat, OCP on gfx950)
__device__ __forceinline__ unsigned int pk4_fp8(float a, float b, float c, float d) {
    unsigned int w = (unsigned int)__builtin_amdgcn_cvt_pk_fp8_f32(a, b, 0, false);
    w = (unsigned int)__builtin_amdgcn_cvt_pk_fp8_f32(c, d, (int)w, true);
    return w;
}

// ---------------------------------------------------------------------------
// prep_fused (R14, measured good): blocks [0,1024) build Lq (fp8 L^T, x256)
// + Woff^2 partials; blocks [1024,1024+16384) cast X->fp8 + pred_mean GEMV.
// ---------------------------------------------------------------------------
__global__ __launch_bounds__(256) void prep_fused(const float* __restrict__ X,
                                                  const float* __restrict__ Wm,
                                                  const float* __restrict__ Woff,
                                                  const float* __restrict__ Wld,
                                                  unsigned char* __restrict__ Xq,
                                                  unsigned char* __restrict__ Lq,
                                                  float* __restrict__ U,
                                                  float* __restrict__ misc_arr) {
    __shared__ float tile[64][65];
    __shared__ float red[4];
    const int bid = blockIdx.x;
    const int tid = threadIdx.x;

    if (bid < 1024) {
        const int jt = (bid & 31) * 64;
        const int it = (bid >> 5) * 64;
        float ss = 0.f;
        if (it + 63 >= jt) {
            for (int e = tid; e < 4096; e += 256) {
                int r = e >> 6, c = e & 63;
                tile[r][c] = Woff[(size_t)(it + r) * K_DIM + (jt + c)];
            }
        }
        __syncthreads();
        for (int e = tid; e < 4096; e += 256) {
            int jr = e >> 6, ic = e & 63;
            int i = it + ic, j = jt + jr;
            float v = 0.f;
            if (i > j) { v = tile[ic][jr]; ss += v * v; }
            else if (i == j) v = expf(Wld[i]);
            unsigned int w = (unsigned int)__builtin_amdgcn_cvt_pk_fp8_f32(v * LSCALE, 0.f, 0, false);
            Lq[(size_t)j * K_DIM + i] = (unsigned char)(w & 0xffu);
        }
        #pragma unroll
        for (int off = 32; off; off >>= 1) ss += __shfl_down(ss, off);
        if ((tid & 63) == 0) red[tid >> 6] = ss;
        __syncthreads();
        if (tid == 0) misc_arr[bid] = red[0] + red[1] + red[2] + red[3];
    } else {
        const int b = bid - 1024;
        const float* xr = X + (size_t)b * K_DIM;
        unsigned char* xo = Xq + (size_t)b * K_DIM;
        const int base = tid * 8;
        float4 v0 = *(const float4*)(xr + base);
        float4 v1 = *(const float4*)(xr + base + 4);
        float4 w0 = *(const float4*)(Wm + base);
        float4 w1 = *(const float4*)(Wm + base + 4);
        float dot = v0.x * w0.x + v0.y * w0.y + v0.z * w0.z + v0.w * w0.w
                  + v1.x * w1.x + v1.y * w1.y + v1.z * w1.z + v1.w * w1.w;
        uint2 p;
        p.x = pk4_fp8(v0.x, v0.y, v0.z, v0.w);
        p.y = pk4_fp8(v1.x, v1.y, v1.z, v1.w);
        *(uint2*)(xo + base) = p;
        #pragma unroll
        for (int off = 32; off; off >>= 1) dot += __shfl_down(dot, off);
        if ((tid & 63) == 0) red[tid >> 6] = dot;
        __syncthreads();
        if (tid == 0) U[b] = red[0] + red[1] + red[2] + red[3];
    }
}

// ---------------------------------------------------------------------------
// quad_gemm fp8 MX 256x256, BK=128, 2-buf LDS (128 KB), 8 waves (2M x 4N).
// MINIMAL-SYNC variant (R5 skeleton): per K128-unit exactly ONE vmcnt(0) and
// ONE s_barrier; no lgkm fences (compiler emits counted lgkmcnt for
// ds_read->MFMA), no sched_barriers, no mid-unit barriers.
// Safety (R5-proven): reads hit buf[cur] and retire before their consuming
// MFMAs (register dep); MFMAs precede the barrier; stores hit only buf[nbuf];
// vmcnt(0)+barrier gates the swap, so unit t+1's stores into old cur cannot
// race any unretired read.
// ---------------------------------------------------------------------------
__device__ __forceinline__ i32x8 frag128(const unsigned char* base, int roff, int g) {
    const unsigned char* rb = base + roff * 128;
    int x = (roff & 7) << 4;
    i32x4 lo = *(const i32x4*)(rb + (((g * 2) << 4) ^ x));
    i32x4 hi = *(const i32x4*)(rb + (((g * 2 + 1) << 4) ^ x));
    return __builtin_shufflevector(lo, hi, 0, 1, 2, 3, 4, 5, 6, 7);
}

#define MXMFMA(A, B, C) __builtin_amdgcn_mfma_scale_f32_16x16x128_f8f6f4( \
        (A), (B), (C), 0, 0, 0, SCALE_ONE, 0, SCALE_ONE)
#define BAR() asm volatile("s_barrier" ::: "memory")

__global__ __launch_bounds__(512, 2) void quad_gemm(const unsigned char* __restrict__ Xq,
                                                    const unsigned char* __restrict__ Lq,
                                                    float* __restrict__ qpart) {
    __shared__ unsigned char As[2][BM * BK];   // 2 x 32 KB
    __shared__ unsigned char Bs[2][BN * BK];   // 2 x 32 KB (128 KB total)

    const int mb = blockIdx.x;
    const int jp = blockIdx.y;              // 0..3
    const int tid = threadIdx.x;
    const int lane = tid & 63;
    const int wid = tid >> 6;               // 0..7
    const int wr = wid >> 2, wc = wid & 3;  // 2M x 4N wave grid
    const int g = lane >> 4, r16 = lane & 15;
    const int brow = mb * BM;
    const int srow = lane >> 3;             // 0..7 == (lds row & 7)
    const int scol = (lane & 7) ^ srow;     // pre-swizzled 16B source chunk

    auto gemm_one = [&](int nb) {
        const int bcol = nb * BN;
        const int NT = (K_DIM - bcol) >> 7;   // 16 - 2*nb, in [2,16]

        const unsigned char* pA[2];
        const unsigned char* pB[2];
        #pragma unroll
        for (int h = 0; h < 2; ++h) {
            pA[h] = Xq + (size_t)(brow + h * 128 + wid * 16 + srow) * K_DIM + bcol + scol * 16;
            pB[h] = Lq + (size_t)(bcol + h * 128 + wid * 16 + srow) * K_DIM + bcol + scol * 16;
        }
        auto stgA = [&](int t, int h, int buf) {
            const unsigned char* s = pA[h] + (size_t)t * 128;
            char* d = (char*)As[buf] + h * 16384 + wid * 2048;
            gload16(s, d);
            gload16(s + (size_t)8 * K_DIM, d + 1024);
        };
        auto stgB = [&](int t, int h, int buf) {
            const unsigned char* s = pB[h] + (size_t)t * 128;
            char* d = (char*)Bs[buf] + h * 16384 + wid * 2048;
            gload16(s, d);
            gload16(s + (size_t)8 * K_DIM, d + 1024);
        };

        f32x4 acc[8][4];
        const f32x4 zero = {0.f, 0.f, 0.f, 0.f};
        #pragma unroll
        for (int m = 0; m < 8; ++m)
            #pragma unroll
            for (int n = 0; n < 4; ++n) acc[m][n] = zero;

        // prologue: unit 0 -> buf 0
        stgA(0, 0, 0); stgA(0, 1, 0); stgB(0, 0, 0); stgB(0, 1, 0);
        asm volatile("s_waitcnt vmcnt(0)" ::: "memory");
        BAR();

        for (int t = 0; t < NT; ++t) {
            const int cur = t & 1, nbuf = cur ^ 1;
            const unsigned char* Abase = As[cur] + wr * 16384;
            const unsigned char* Bbase = Bs[cur] + (wc >> 1) * 16384;
            const int brow2 = (wc & 1) * 64;
            const bool s1 = (t + 1 < NT);

            // stage ALL of unit t+1 now (dest buffer idle since the barrier)
            if (s1) {
                stgA(t + 1, 0, nbuf); stgA(t + 1, 1, nbuf);
                stgB(t + 1, 0, nbuf); stgB(t + 1, 1, nbuf);
            }

            i32x8 bf[4], af[4];
            #pragma unroll
            for (int n = 0; n < 4; ++n) bf[n] = frag128(Bbase, brow2 + n * 16 + r16, g);
            #pragma unroll
            for (int m = 0; m < 4; ++m) af[m] = frag128(Abase, m * 16 + r16, g);
            __builtin_amdgcn_s_setprio(1);
            #pragma unroll
            for (int m = 0; m < 4; ++m)
                #pragma unroll
                for (int n = 0; n < 4; ++n)
                    acc[m][n] = MXMFMA(af[m], bf[n], acc[m][n]);
            __builtin_amdgcn_s_setprio(0);

            #pragma unroll
            for (int m = 0; m < 4; ++m) af[m] = frag128(Abase, 64 + m * 16 + r16, g);
            __builtin_amdgcn_s_setprio(1);
            #pragma unroll
            for (int m = 0; m < 4; ++m)
                #pragma unroll
                for (int n = 0; n < 4; ++n)
                    acc[4 + m][n] = MXMFMA(af[m], bf[n], acc[4 + m][n]);
            __builtin_amdgcn_s_setprio(0);

            // unit end: one drain (loads issued a full unit ago) + one barrier
            if (s1)
                asm volatile("s_waitcnt vmcnt(0)" ::: "memory");
            BAR();
        }

        float* qbuf = (float*)&As[0][0];
        __syncthreads();
        #pragma unroll
        for (int m = 0; m < 8; ++m) {
            #pragma unroll
            for (int r = 0; r < 4; ++r) {
                float s = 0.f;
                #pragma unroll
                for (int n = 0; n < 4; ++n) {
                    float t2 = acc[m][n][r];
                    s += t2 * t2;
                }
                #pragma unroll
                for (int off = 1; off < 16; off <<= 1) s += __shfl_xor(s, off);
                if (r16 == 0) qbuf[wc * 256 + wr * 128 + m * 16 + g * 4 + r] = s;
            }
        }
        __syncthreads();
        if (tid < BM)
            qpart[(size_t)(brow + tid) * NB_N + nb] =
                (qbuf[tid] + qbuf[256 + tid] + qbuf[512 + tid] + qbuf[768 + tid]) * QDESCALE;
        __syncthreads();
    };

    gemm_one(jp);        // heavy: NT = 16 - 2*jp
    gemm_one(7 - jp);    // light: NT = 2 + 2*jp; sum = 18 always
}
#undef BAR

// ---------------------------------------------------------------------------
// row_part: 128 blocks x 256 threads, 128 rows each (XCD-spread qpart read).
// ---------------------------------------------------------------------------
__global__ __launch_bounds__(256) void row_part(const float* __restrict__ Y,
                                                const float* __restrict__ Cnt,
                                                const float* __restrict__ nld_p,
                                                const float* __restrict__ U,
                                                const float* __restrict__ qpart,
                                                double* __restrict__ dpart) {
    const int tid = threadIdx.x;
    const float nld = nld_p[0];
    const float inv_sig = expf(-nld);
    const float nprec = inv_sig * inv_sig;
    double s1 = 0.0, s2 = 0.0;
    if (tid < 128) {
        const int b = blockIdx.x * 128 + tid;
        float c = Cnt[b];
        const float4* qp = (const float4*)(qpart + (size_t)b * NB_N);
        float4 q0 = qp[0], q1 = qp[1];
        float q = q0.x + q0.y + q0.z + q0.w + q1.x + q1.y + q1.z + q1.w;
        float d = (Y[b] - U[b]) * inv_sig;
        float pl = -0.5f * d * d - nld - 0.5f * LOG2PI_F;
        float tt = 0.5f * q * c * c * nprec;
        s1 = (double)c;
        s2 = (double)((pl - tt) * c);
    }
    __shared__ double red[2][4];
    #pragma unroll
    for (int off = 32; off; off >>= 1) {
        s1 += __shfl_down(s1, off);
        s2 += __shfl_down(s2, off);
    }
    if ((tid & 63) == 0) { red[0][tid >> 6] = s1; red[1][tid >> 6] = s2; }
    __syncthreads();
    if (tid == 0) {
        dpart[blockIdx.x * 2 + 0] = red[0][0] + red[0][1] + red[0][2] + red[0][3];
        dpart[blockIdx.x * 2 + 1] = red[1][0] + red[1][1] + red[1][2] + red[1][3];
    }
}

// ---------------------------------------------------------------------------
// finalize2: combine 128 partials + KL/wishart scalar terms. One block.
// ---------------------------------------------------------------------------
__global__ __launch_bounds__(256) void finalize2(const float* __restrict__ nld_p,
                                                 const float* __restrict__ Wm,
                                                 const float* __restrict__ Wld,
                                                 const double* __restrict__ dpart,
                                                 const float* __restrict__ misc_arr,
                                                 float* __restrict__ out) {
    const int tid = threadIdx.x;
    const float nld = nld_p[0];
    const float inv_sig = expf(-nld);
    const float nprec = inv_sig * inv_sig;

    double s1 = 0.0, s2 = 0.0;
    if (tid < 128) { s1 = dpart[tid * 2]; s2 = dpart[tid * 2 + 1]; }

    double wm2 = 0.0, tcd = 0.0, wls = 0.0, offs = 0.0;
    for (int i = tid; i < K_DIM; i += 256) {
        float w = Wm[i];
        wm2 += (double)w * (double)w;
        float ld = Wld[i];
        tcd += exp(2.0 * (double)ld);
        wls += (double)ld;
    }
    for (int i = tid; i < 1024; i += 256) offs += (double)misc_arr[i];

    __shared__ double red[6][4];
    double vals[6] = {s1, s2, wm2, tcd, wls, offs};
    #pragma unroll
    for (int s = 0; s < 6; ++s) {
        double v = vals[s];
        #pragma unroll
        for (int off = 32; off; off >>= 1) v += __shfl_down(v, off);
        if ((tid & 63) == 0) red[s][tid >> 6] = v;
    }
    __syncthreads();
    if (tid == 0) {
        double S1 = red[0][0] + red[0][1] + red[0][2] + red[0][3];
        double S2 = red[1][0] + red[1][1] + red[1][2] + red[1][3];
        double MSE = red[2][0] + red[2][1] + red[2][2] + red[2][3];
        double TCD = red[3][0] + red[3][1] + red[3][2] + red[3][3];
        double WLS = red[4][0] + red[4][1] + red[4][2] + red[4][3];
        double OFFS = red[5][0] + red[5][1] + red[5][2] + red[5][3];
        double trace_cov = OFFS + TCD;
        double kl = 0.5 * (MSE + trace_cov - 2.0 * WLS);
        double wish = 1.5 * (-2.0 * (double)nld) - 0.005 * (double)nprec;
        double elbo = S2 / S1 + 1e-4 * (wish - kl);
        out[0] = (float)(-elbo);
    }
}

// ---------------------------------------------------------------------------
extern "C" void kernel_launch(void* const* d_in, const int* in_sizes, int n_in,
                              void* d_out, int out_size, void* d_ws, size_t ws_size,
                              hipStream_t stream) {
    const float* x    = (const float*)d_in[0];
    const float* y    = (const float*)d_in[1];
    const float* cnt  = (const float*)d_in[2];
    // d_in[3] = noise_mean (unused by the reference math)
    const float* nld  = (const float*)d_in[4];
    const float* Wm   = (const float*)d_in[5];
    const float* Wld  = (const float*)d_in[6];
    const float* Woff = (const float*)d_in[7];

    char* ws = (char*)d_ws;
    unsigned char* Xq = (unsigned char*)(ws);              // 33554432 B
    unsigned char* Lq = (unsigned char*)(ws + 33554432);   // 4194304 B
    double* dpart  = (double*)(ws + 40000000);             // 2048 B
    float*  U      = (float*)(ws + 75497472);              // 64 KB
    float*  qpart  = (float*)(ws + 75563008);              // 512 KB
    float*  misc   = (float*)(ws + 76611584);              // 4 KB

    prep_fused<<<dim3(1024 + M_DIM), 256, 0, stream>>>(x, Wm, Woff, Wld, Xq, Lq, U, misc);
    quad_gemm<<<dim3(NB_M, 4), 512, 0, stream>>>(Xq, Lq, qpart);
    row_part<<<dim3(128), 256, 0, stream>>>(y, cnt, nld, U, qpart, dpart);
    finalize2<<<1, 256, 0, stream>>>(nld, Wm, Wld, dpart, misc, (float*)d_out);
}